// Round 11
// baseline (195.612 us; speedup 1.0000x reference)
//
#include <hip/hip_runtime.h>
#include <hip/hip_bf16.h>

// B=8192, S=200, E=8, H1=64, H2=32
// att_in = [q, h, q-h, q*h] (32) -> relu(@W1[32,64]+b1) -> relu(@W2[64,32]+b2)
// score = @W3[32,1]+b3 ; mask s<len ; out[b,:] = sum_s score*hist[b,s,:]
//
// Transposed chain: h1^T = W1^T att^T ; h2^T = W2^T relu(h1)^T.
// pi-trick: W1 columns (and b1) pre-permuted so stage-1 MFMA D-layout IS the
// stage-2 B-frag layout -> zero LDS, zero transpose shuffles.
// This round: __launch_bounds__(256,4) to force the UNIFIED VGPR+AGPR budget
// under 128/wave (occupancy theory: unreported AGPRs were capping residency).
#define BB 8192
#define SS 200

typedef __attribute__((ext_vector_type(8))) short short8;   // bf16x8 MFMA frag
typedef __attribute__((ext_vector_type(4))) float f32x4;    // fp32x4 MFMA acc

__device__ __forceinline__ unsigned short f2bf(float f) {
    union { float f; unsigned int u; } v; v.f = f;
    unsigned int r = v.u + 0x7FFFu + ((v.u >> 16) & 1u);    // RNE
    return (unsigned short)(r >> 16);
}
// pack 2 fp32 -> 1 u32 of 2 bf16 (v_cvt_pk_bf16_f32)
__device__ __forceinline__ unsigned int packbf2(float a, float b) {
    union { __hip_bfloat162 h; unsigned int u; } v;
    v.h = __float22bfloat162_rn(make_float2(a, b));
    return v.u;
}

// ---- prep (2 blocks: 0 -> W1, 1 -> W2) ----
// wsW1[(n*64+l)*8+j] = W1[8g+j][pi(16n+c)]          pi(16n+c) = 32(n&1)+8(c>>2)+4(n>>1)+(c&3)
// wsW2[((kc*2+n)*64+l)*8+j] = W2[32kc+8g+j][16n+c]
__global__ void prep_kernel(const float* __restrict__ W1, const float* __restrict__ W2,
                            unsigned short* __restrict__ wsW1,
                            unsigned short* __restrict__ wsW2) {
    int t = threadIdx.x;             // 0..255
    int l = t & 63;
    int g = l >> 4, c = l & 15;
    if (blockIdx.x == 0) {
        int n = t >> 6;              // 0..3
        int pcol = 32 * (n & 1) + 8 * (c >> 2) + 4 * (n >> 1) + (c & 3);   // pi(16n + c)
#pragma unroll
        for (int j = 0; j < 8; ++j)
            wsW1[(n * 64 + l) * 8 + j] = f2bf(W1[(8 * g + j) * 64 + pcol]);
    } else {
        int kc = t >> 7, n = (t >> 6) & 1;
#pragma unroll
        for (int j = 0; j < 8; ++j)
            wsW2[((kc * 2 + n) * 64 + l) * 8 + j] = f2bf(W2[(32 * kc + 8 * g + j) * 32 + 16 * n + c]);
    }
}

// ---- main: 4 waves/block; wave owns one batch row; 13 subtiles fully unrolled ----
__global__ __launch_bounds__(256, 4)
void din8_kernel(const float* __restrict__ query,       // [B,1,8]
                 const float* __restrict__ hist,        // [B,200,8]
                 const int* __restrict__ hlen,          // [B] int32
                 const unsigned short* __restrict__ wsW1,
                 const unsigned short* __restrict__ wsW2,
                 const float* __restrict__ b1,          // [64]
                 const float* __restrict__ b2,          // [32]
                 const float* __restrict__ W3,          // [32]
                 const float* __restrict__ b3,          // [1]
                 float* __restrict__ out)               // [B,1,8]
{
    const int tid  = threadIdx.x;
    const int wave = tid >> 6;
    const int l    = tid & 63;
    const int g    = l >> 4;     // k-block group
    const int c    = l & 15;     // position-within-subtile
    const int brow = blockIdx.x * 4 + wave;

    const int len = hlen[brow];

    short8 w1f[4];
#pragma unroll
    for (int n = 0; n < 4; ++n)
        w1f[n] = *reinterpret_cast<const short8*>(wsW1 + (n * 64 + l) * 8);
    short8 w2tf[2][2];
#pragma unroll
    for (int kc = 0; kc < 2; ++kc)
#pragma unroll
        for (int n2 = 0; n2 < 2; ++n2)
            w2tf[kc][n2] = *reinterpret_cast<const short8*>(wsW2 + ((kc * 2 + n2) * 64 + l) * 8);

    // permuted b1 as stage-1 C-operand: b1c[n][r] = b1[pi(16n+4g+r)] = b1[32(n&1)+4(n>>1)+8g+r]
    f32x4 b1c[4];
#pragma unroll
    for (int n = 0; n < 4; ++n)
        b1c[n] = *reinterpret_cast<const f32x4*>(b1 + 32 * (n & 1) + 4 * (n >> 1) + 8 * g);
    f32x4 b2c[2], W3v[2];
#pragma unroll
    for (int n2 = 0; n2 < 2; ++n2) {
        b2c[n2] = *reinterpret_cast<const f32x4*>(b2 + 16 * n2 + 4 * g);
        W3v[n2] = *reinterpret_cast<const f32x4*>(W3 + 16 * n2 + 4 * g);
    }
    const float b3s = b3[0];

    const float4* qp = reinterpret_cast<const float4*>(query + (size_t)brow * 8);
    float4 qa = qp[0], qb = qp[1];
    float q[8] = {qa.x, qa.y, qa.z, qa.w, qb.x, qb.y, qb.z, qb.w};

    const float* hrow = hist + (size_t)brow * SS * 8;
    float accO[8];
#pragma unroll
    for (int e = 0; e < 8; ++e) accO[e] = 0.0f;

    float hreg[13][8];   // fully-unrolled -> static indices; ~3 live at a time

    auto loadH = [&](int x) {
        const float4* p = reinterpret_cast<const float4*>(hrow + (size_t)min(16 * x + c, SS - 1) * 8);
        float4 v0 = p[0], v1 = p[1];
        float* h = hreg[x];
        h[0]=v0.x; h[1]=v0.y; h[2]=v0.z; h[3]=v0.w;
        h[4]=v1.x; h[5]=v1.y; h[6]=v1.z; h[7]=v1.w;
    };

    // att value for this lane's k-block, recomputed from q (register diet):
    //   g=0: q ; g=1: h ; g=2: q-h ; g=3: q*h
    auto attv = [&](int j, float hj) -> float {
        return (g == 0) ? q[j]
             : (g == 1) ? hj
             : (g == 2) ? (q[j] - hj)
                        : (q[j] * hj);
    };

    auto compute = [&](int x) {
        const float* h = hreg[x];
        union { unsigned int u[4]; short8 s; } uf;
#pragma unroll
        for (int m = 0; m < 4; ++m)
            uf.u[m] = packbf2(attv(2 * m, h[2 * m]), attv(2 * m + 1, h[2 * m + 1]));

        // stage 1': permuted h1^T = (P W1^T) @ att^T, bias in C
        f32x4 a1[4];
#pragma unroll
        for (int n = 0; n < 4; ++n)
            a1[n] = __builtin_amdgcn_mfma_f32_16x16x32_bf16(w1f[n], uf.s, b1c[n], 0, 0, 0);

        // relu + pack DIRECTLY into stage-2 B-frags (pi makes layouts coincide)
        union { unsigned int u[4]; short8 s; } hb0, hb1;
#pragma unroll
        for (int q2 = 0; q2 < 2; ++q2) {
            hb0.u[q2]     = packbf2(fmaxf(a1[0][2*q2], 0.f), fmaxf(a1[0][2*q2+1], 0.f));
            hb0.u[2 + q2] = packbf2(fmaxf(a1[2][2*q2], 0.f), fmaxf(a1[2][2*q2+1], 0.f));
            hb1.u[q2]     = packbf2(fmaxf(a1[1][2*q2], 0.f), fmaxf(a1[1][2*q2+1], 0.f));
            hb1.u[2 + q2] = packbf2(fmaxf(a1[3][2*q2], 0.f), fmaxf(a1[3][2*q2+1], 0.f));
        }

        // stage 2': h2^T = W2^T @ relu(h1)^T, bias in C
        f32x4 a2[2];
#pragma unroll
        for (int n2 = 0; n2 < 2; ++n2) {
            a2[n2] = __builtin_amdgcn_mfma_f32_16x16x32_bf16(w2tf[0][n2], hb0.s, b2c[n2], 0, 0, 0);
            a2[n2] = __builtin_amdgcn_mfma_f32_16x16x32_bf16(w2tf[1][n2], hb1.s, a2[n2], 0, 0, 0);
        }

        // stage 3: lane-local dot with W3, 2-hop butterfly over g-copies
        float p0 = 0.f, p1 = 0.f;
#pragma unroll
        for (int r = 0; r < 4; ++r) {
            p0 = fmaf(fmaxf(a2[0][r], 0.f), W3v[0][r], p0);
            p1 = fmaf(fmaxf(a2[1][r], 0.f), W3v[1][r], p1);
        }
        float p = p0 + p1;
        p += __shfl_xor(p, 16); p += __shfl_xor(p, 32);
        float sc = (16 * x + c < len) ? (p + b3s) : 0.0f;

        // pooling (fp32 hist already in the right lanes)
#pragma unroll
        for (int e = 0; e < 8; ++e) accO[e] = fmaf(sc, h[e], accO[e]);
    };

    // ---- pipeline: load(t+2) | compute(t), fully unrolled ----
    loadH(0);
    loadH(1);
#pragma unroll
    for (int it = 0; it < 13; ++it) {
        if (it + 2 < 13) loadH(it + 2);
        compute(it);
    }

    // ---- reduce over the 16 position-lanes (g-copies identical) ----
#pragma unroll
    for (int m = 1; m < 16; m <<= 1)
#pragma unroll
        for (int e = 0; e < 8; ++e) accO[e] += __shfl_xor(accO[e], m);

    if (l == 0) {
        float4* op = reinterpret_cast<float4*>(out + (size_t)brow * 8);
        op[0] = make_float4(accO[0], accO[1], accO[2], accO[3]);
        op[1] = make_float4(accO[4], accO[5], accO[6], accO[7]);
    }
}

extern "C" void kernel_launch(void* const* d_in, const int* in_sizes, int n_in,
                              void* d_out, int out_size, void* d_ws, size_t ws_size,
                              hipStream_t stream) {
    const float* query = (const float*)d_in[0];
    const float* hist  = (const float*)d_in[1];
    const int*   hlen  = (const int*)d_in[2];
    const float* W1    = (const float*)d_in[3];
    const float* b1    = (const float*)d_in[4];
    const float* W2    = (const float*)d_in[5];
    const float* b2    = (const float*)d_in[6];
    const float* W3    = (const float*)d_in[7];
    const float* b3    = (const float*)d_in[8];
    float*       out   = (float*)d_out;

    unsigned short* wsW1 = (unsigned short*)d_ws;          // 4KB
    unsigned short* wsW2 = wsW1 + 4 * 64 * 8;              // 4KB

    prep_kernel<<<2, 256, 0, stream>>>(W1, W2, wsW1, wsW2);
    din8_kernel<<<BB / 4, 256, 0, stream>>>(query, hist, hlen, wsW1, wsW2,
                                            b1, b2, W3, b3, out);
}

// Round 12
// 44.959 us; speedup vs baseline: 4.3509x; 4.3509x over previous
//
#include <hip/hip_runtime.h>
#include <hip/hip_bf16.h>

// B=8192, S=200, E=8, H1=64, H2=32
// att_in = [q, h, q-h, q*h] (32) -> relu(@W1[32,64]+b1) -> relu(@W2[64,32]+b2)
// score = @W3[32,1]+b3 ; mask s<len ; out[b,:] = sum_s score*hist[b,s,:]
//
// Transposed chain: h1^T = W1^T att^T ; h2^T = W2^T relu(h1)^T.
// pi-trick: W1 columns + b1 pre-permuted so stage-1 MFMA D-layout IS the
// stage-2 B-frag layout (zero LDS, zero transpose shuffles).
// This round: explicit 2-stage software pipeline S1(t+1) || S2(t) to give the
// scheduler two register-disjoint dependency chains per iteration (2 waves/SIMD
// cap is structural -> buy latency tolerance with ILP, not occupancy).
#define BB 8192
#define SS 200

typedef __attribute__((ext_vector_type(8))) short short8;   // bf16x8 MFMA frag
typedef __attribute__((ext_vector_type(4))) float f32x4;    // fp32x4 MFMA acc

__device__ __forceinline__ unsigned short f2bf(float f) {
    union { float f; unsigned int u; } v; v.f = f;
    unsigned int r = v.u + 0x7FFFu + ((v.u >> 16) & 1u);    // RNE
    return (unsigned short)(r >> 16);
}
// pack 2 fp32 -> 1 u32 of 2 bf16 (v_cvt_pk_bf16_f32)
__device__ __forceinline__ unsigned int packbf2(float a, float b) {
    union { __hip_bfloat162 h; unsigned int u; } v;
    v.h = __float22bfloat162_rn(make_float2(a, b));
    return v.u;
}

// ---- prep (2 blocks: 0 -> W1, 1 -> W2) ----
// wsW1[(n*64+l)*8+j] = W1[8g+j][pi(16n+c)],  pi(16n+c) = 32(n&1)+8(c>>2)+4(n>>1)+(c&3)
// wsW2[((kc*2+n)*64+l)*8+j] = W2[32kc+8g+j][16n+c]
__global__ void prep_kernel(const float* __restrict__ W1, const float* __restrict__ W2,
                            unsigned short* __restrict__ wsW1,
                            unsigned short* __restrict__ wsW2) {
    int t = threadIdx.x;             // 0..255
    int l = t & 63;
    int g = l >> 4, c = l & 15;
    if (blockIdx.x == 0) {
        int n = t >> 6;              // 0..3
        int pcol = 32 * (n & 1) + 8 * (c >> 2) + 4 * (n >> 1) + (c & 3);   // pi(16n + c)
#pragma unroll
        for (int j = 0; j < 8; ++j)
            wsW1[(n * 64 + l) * 8 + j] = f2bf(W1[(8 * g + j) * 64 + pcol]);
    } else {
        int kc = t >> 7, n = (t >> 6) & 1;
#pragma unroll
        for (int j = 0; j < 8; ++j)
            wsW2[((kc * 2 + n) * 64 + l) * 8 + j] = f2bf(W2[(32 * kc + 8 * g + j) * 32 + 16 * n + c]);
    }
}

// ---- main: 4 waves/block; wave owns one batch row; 13 subtiles, fully unrolled ----
__global__ __launch_bounds__(256)
void din9_kernel(const float* __restrict__ query,       // [B,1,8]
                 const float* __restrict__ hist,        // [B,200,8]
                 const int* __restrict__ hlen,          // [B] int32
                 const unsigned short* __restrict__ wsW1,
                 const unsigned short* __restrict__ wsW2,
                 const float* __restrict__ b1,          // [64]
                 const float* __restrict__ b2,          // [32]
                 const float* __restrict__ W3,          // [32]
                 const float* __restrict__ b3,          // [1]
                 float* __restrict__ out)               // [B,1,8]
{
    const int tid  = threadIdx.x;
    const int wave = tid >> 6;
    const int l    = tid & 63;
    const int g    = l >> 4;     // k-block group
    const int c    = l & 15;     // position-within-subtile
    const int brow = blockIdx.x * 4 + wave;

    const int len = hlen[brow];

    short8 w1f[4];
#pragma unroll
    for (int n = 0; n < 4; ++n)
        w1f[n] = *reinterpret_cast<const short8*>(wsW1 + (n * 64 + l) * 8);
    short8 w2tf[2][2];
#pragma unroll
    for (int kc = 0; kc < 2; ++kc)
#pragma unroll
        for (int n2 = 0; n2 < 2; ++n2)
            w2tf[kc][n2] = *reinterpret_cast<const short8*>(wsW2 + ((kc * 2 + n2) * 64 + l) * 8);

    // permuted b1 as stage-1 C-operand: b1c[n][r] = b1[pi(16n+4g+r)] = b1[32(n&1)+4(n>>1)+8g+r]
    f32x4 b1c[4];
#pragma unroll
    for (int n = 0; n < 4; ++n)
        b1c[n] = *reinterpret_cast<const f32x4*>(b1 + 32 * (n & 1) + 4 * (n >> 1) + 8 * g);
    f32x4 b2c[2], W3v[2];
#pragma unroll
    for (int n2 = 0; n2 < 2; ++n2) {
        b2c[n2] = *reinterpret_cast<const f32x4*>(b2 + 16 * n2 + 4 * g);
        W3v[n2] = *reinterpret_cast<const f32x4*>(W3 + 16 * n2 + 4 * g);
    }
    const float b3s = b3[0];

    // att fold: v = aq[j] + bcv[j]*h[j]  (aq = alpha*q, bcv = beta + gamma*q)
    const float alpha = (g == 0 || g == 2) ? 1.0f : 0.0f;
    const float beta  = (g == 1) ? 1.0f : ((g == 2) ? -1.0f : 0.0f);
    const float gamma = (g == 3) ? 1.0f : 0.0f;
    const float4* qp = reinterpret_cast<const float4*>(query + (size_t)brow * 8);
    float4 qa = qp[0], qb = qp[1];
    float q[8] = {qa.x, qa.y, qa.z, qa.w, qb.x, qb.y, qb.z, qb.w};
    float aq[8], bcv[8];
#pragma unroll
    for (int j = 0; j < 8; ++j) { aq[j] = alpha * q[j]; bcv[j] = beta + gamma * q[j]; }

    const float* hrow = hist + (size_t)brow * SS * 8;
    float accO[8];
#pragma unroll
    for (int e = 0; e < 8; ++e) accO[e] = 0.0f;

    float hreg[13][8];   // fully-unrolled -> static indices; ~4 slots live

    auto loadH = [&](int x) {
        const float4* p = reinterpret_cast<const float4*>(hrow + (size_t)min(16 * x + c, SS - 1) * 8);
        float4 v0 = p[0], v1 = p[1];
        float* h = hreg[x];
        h[0]=v0.x; h[1]=v0.y; h[2]=v0.z; h[3]=v0.w;
        h[4]=v1.x; h[5]=v1.y; h[6]=v1.z; h[7]=v1.w;
    };

    // pipeline state: stage-2 B-frags for two subtile parities (static [x&1] idx)
    union u_s8 { unsigned int u[4]; short8 s; };
    u_s8 hb0_[2], hb1_[2];

    // S1: att-pack -> stage-1' MFMA (4x) -> relu+pack into hb frags
    auto S1 = [&](int x) {
        const float* h = hreg[x];
        u_s8 uf;
#pragma unroll
        for (int m = 0; m < 4; ++m)
            uf.u[m] = packbf2(fmaf(bcv[2*m], h[2*m], aq[2*m]),
                              fmaf(bcv[2*m+1], h[2*m+1], aq[2*m+1]));
        f32x4 a1[4];
#pragma unroll
        for (int n = 0; n < 4; ++n)
            a1[n] = __builtin_amdgcn_mfma_f32_16x16x32_bf16(w1f[n], uf.s, b1c[n], 0, 0, 0);
        u_s8& hb0 = hb0_[x & 1];
        u_s8& hb1 = hb1_[x & 1];
#pragma unroll
        for (int q2 = 0; q2 < 2; ++q2) {
            hb0.u[q2]     = packbf2(fmaxf(a1[0][2*q2], 0.f), fmaxf(a1[0][2*q2+1], 0.f));
            hb0.u[2 + q2] = packbf2(fmaxf(a1[2][2*q2], 0.f), fmaxf(a1[2][2*q2+1], 0.f));
            hb1.u[q2]     = packbf2(fmaxf(a1[1][2*q2], 0.f), fmaxf(a1[1][2*q2+1], 0.f));
            hb1.u[2 + q2] = packbf2(fmaxf(a1[3][2*q2], 0.f), fmaxf(a1[3][2*q2+1], 0.f));
        }
    };

    // S2: stage-2' MFMA (4x) -> W3 dot -> butterfly -> mask -> pool
    auto S2 = [&](int x) {
        const float* h = hreg[x];
        u_s8& hb0 = hb0_[x & 1];
        u_s8& hb1 = hb1_[x & 1];
        f32x4 a2[2];
#pragma unroll
        for (int n2 = 0; n2 < 2; ++n2) {
            a2[n2] = __builtin_amdgcn_mfma_f32_16x16x32_bf16(w2tf[0][n2], hb0.s, b2c[n2], 0, 0, 0);
            a2[n2] = __builtin_amdgcn_mfma_f32_16x16x32_bf16(w2tf[1][n2], hb1.s, a2[n2], 0, 0, 0);
        }
        float p0 = 0.f, p1 = 0.f;
#pragma unroll
        for (int r = 0; r < 4; ++r) {
            p0 = fmaf(fmaxf(a2[0][r], 0.f), W3v[0][r], p0);
            p1 = fmaf(fmaxf(a2[1][r], 0.f), W3v[1][r], p1);
        }
        float p = p0 + p1;
        p += __shfl_xor(p, 16); p += __shfl_xor(p, 32);
        float sc = (16 * x + c < len) ? (p + b3s) : 0.0f;
#pragma unroll
        for (int e = 0; e < 8; ++e) accO[e] = fmaf(sc, h[e], accO[e]);
    };

    // ---- pipeline: load(t+3) | S1(t+1) | S2(t), fully unrolled ----
    loadH(0);
    loadH(1);
    loadH(2);
    S1(0);
#pragma unroll
    for (int it = 0; it < 13; ++it) {
        if (it + 3 < 13) loadH(it + 3);
        if (it + 1 < 13) S1(it + 1);
        S2(it);
    }

    // ---- reduce over the 16 position-lanes (g-copies identical) ----
#pragma unroll
    for (int m = 1; m < 16; m <<= 1)
#pragma unroll
        for (int e = 0; e < 8; ++e) accO[e] += __shfl_xor(accO[e], m);

    if (l == 0) {
        float4* op = reinterpret_cast<float4*>(out + (size_t)brow * 8);
        op[0] = make_float4(accO[0], accO[1], accO[2], accO[3]);
        op[1] = make_float4(accO[4], accO[5], accO[6], accO[7]);
    }
}

extern "C" void kernel_launch(void* const* d_in, const int* in_sizes, int n_in,
                              void* d_out, int out_size, void* d_ws, size_t ws_size,
                              hipStream_t stream) {
    const float* query = (const float*)d_in[0];
    const float* hist  = (const float*)d_in[1];
    const int*   hlen  = (const int*)d_in[2];
    const float* W1    = (const float*)d_in[3];
    const float* b1    = (const float*)d_in[4];
    const float* W2    = (const float*)d_in[5];
    const float* b2    = (const float*)d_in[6];
    const float* W3    = (const float*)d_in[7];
    const float* b3    = (const float*)d_in[8];
    float*       out   = (float*)d_out;

    unsigned short* wsW1 = (unsigned short*)d_ws;          // 4KB
    unsigned short* wsW2 = wsW1 + 4 * 64 * 8;              // 4KB

    prep_kernel<<<2, 256, 0, stream>>>(W1, W2, wsW1, wsW2);
    din9_kernel<<<BB / 4, 256, 0, stream>>>(query, hist, hlen, wsW1, wsW2,
                                            b1, b2, W3, b3, out);
}

// Round 13
// 43.058 us; speedup vs baseline: 4.5430x; 1.0442x over previous
//
#include <hip/hip_runtime.h>
#include <hip/hip_bf16.h>

// B=8192, S=200, E=8, H1=64, H2=32
// att_in = [q, h, q-h, q*h] (32) -> relu(@W1[32,64]+b1) -> relu(@W2[64,32]+b2)
// score = @W3[32,1]+b3 ; mask s<len ; out[b,:] = sum_s score*hist[b,s,:]
//
// Transposed chain: h1^T = W1^T att^T ; h2^T = W2^T relu(h1)^T.
// pi-trick: W1 columns + b1 pre-permuted so stage-1 MFMA D-layout IS the
// stage-2 B-frag layout (zero LDS, zero transpose shuffles).
// This round: fast bf16x2 pack = 2x v_add_u32(0x8000) + 1x v_perm_b32
// (round-half-up) replacing the ~10-instruction software RNE pack that was
// ~half of all VALU issue (measured 210 VALU inst/subtile vs ~70 algorithmic).
#define BB 8192
#define SS 200

typedef __attribute__((ext_vector_type(8))) short short8;   // bf16x8 MFMA frag
typedef __attribute__((ext_vector_type(4))) float f32x4;    // fp32x4 MFMA acc

__device__ __forceinline__ unsigned short f2bf(float f) {
    union { float f; unsigned int u; } v; v.f = f;
    unsigned int r = v.u + 0x7FFFu + ((v.u >> 16) & 1u);    // RNE (prep only)
    return (unsigned short)(r >> 16);
}

// fast pack: low ushort = bf16(a), high ushort = bf16(b); round-half-up.
// 3 VALU: add, add, perm. sel 0x07060302: dst={s1.b2,s1.b3,s0.b2,s0.b3}
__device__ __forceinline__ unsigned int packbf2(float a, float b) {
    union { float f; unsigned int u; } ua, ub;
    ua.f = a; ub.f = b;
    return __builtin_amdgcn_perm(ub.u + 0x8000u, ua.u + 0x8000u, 0x07060302u);
}

// ---- prep (2 blocks: 0 -> W1, 1 -> W2) ----
// wsW1[(n*64+l)*8+j] = W1[8g+j][pi(16n+c)],  pi(16n+c) = 32(n&1)+8(c>>2)+4(n>>1)+(c&3)
// wsW2[((kc*2+n)*64+l)*8+j] = W2[32kc+8g+j][16n+c]
__global__ void prep_kernel(const float* __restrict__ W1, const float* __restrict__ W2,
                            unsigned short* __restrict__ wsW1,
                            unsigned short* __restrict__ wsW2) {
    int t = threadIdx.x;             // 0..255
    int l = t & 63;
    int g = l >> 4, c = l & 15;
    if (blockIdx.x == 0) {
        int n = t >> 6;              // 0..3
        int pcol = 32 * (n & 1) + 8 * (c >> 2) + 4 * (n >> 1) + (c & 3);   // pi(16n + c)
#pragma unroll
        for (int j = 0; j < 8; ++j)
            wsW1[(n * 64 + l) * 8 + j] = f2bf(W1[(8 * g + j) * 64 + pcol]);
    } else {
        int kc = t >> 7, n = (t >> 6) & 1;
#pragma unroll
        for (int j = 0; j < 8; ++j)
            wsW2[((kc * 2 + n) * 64 + l) * 8 + j] = f2bf(W2[(32 * kc + 8 * g + j) * 32 + 16 * n + c]);
    }
}

// ---- main: 4 waves/block; wave owns one batch row; 13 subtiles, fully unrolled ----
__global__ __launch_bounds__(256)
void din10_kernel(const float* __restrict__ query,       // [B,1,8]
                  const float* __restrict__ hist,        // [B,200,8]
                  const int* __restrict__ hlen,          // [B] int32
                  const unsigned short* __restrict__ wsW1,
                  const unsigned short* __restrict__ wsW2,
                  const float* __restrict__ b1,          // [64]
                  const float* __restrict__ b2,          // [32]
                  const float* __restrict__ W3,          // [32]
                  const float* __restrict__ b3,          // [1]
                  float* __restrict__ out)               // [B,1,8]
{
    const int tid  = threadIdx.x;
    const int wave = tid >> 6;
    const int l    = tid & 63;
    const int g    = l >> 4;     // k-block group
    const int c    = l & 15;     // position-within-subtile
    const int brow = blockIdx.x * 4 + wave;

    const int len = hlen[brow];

    short8 w1f[4];
#pragma unroll
    for (int n = 0; n < 4; ++n)
        w1f[n] = *reinterpret_cast<const short8*>(wsW1 + (n * 64 + l) * 8);
    short8 w2tf[2][2];
#pragma unroll
    for (int kc = 0; kc < 2; ++kc)
#pragma unroll
        for (int n2 = 0; n2 < 2; ++n2)
            w2tf[kc][n2] = *reinterpret_cast<const short8*>(wsW2 + ((kc * 2 + n2) * 64 + l) * 8);

    // permuted b1 as stage-1 C-operand: b1c[n][r] = b1[pi(16n+4g+r)] = b1[32(n&1)+4(n>>1)+8g+r]
    f32x4 b1c[4];
#pragma unroll
    for (int n = 0; n < 4; ++n)
        b1c[n] = *reinterpret_cast<const f32x4*>(b1 + 32 * (n & 1) + 4 * (n >> 1) + 8 * g);
    f32x4 b2c[2], W3v[2];
#pragma unroll
    for (int n2 = 0; n2 < 2; ++n2) {
        b2c[n2] = *reinterpret_cast<const f32x4*>(b2 + 16 * n2 + 4 * g);
        W3v[n2] = *reinterpret_cast<const f32x4*>(W3 + 16 * n2 + 4 * g);
    }
    const float b3s = b3[0];

    // att fold: v = aq[j] + bcv[j]*h[j]  (aq = alpha*q, bcv = beta + gamma*q)
    const float alpha = (g == 0 || g == 2) ? 1.0f : 0.0f;
    const float beta  = (g == 1) ? 1.0f : ((g == 2) ? -1.0f : 0.0f);
    const float gamma = (g == 3) ? 1.0f : 0.0f;
    const float4* qp = reinterpret_cast<const float4*>(query + (size_t)brow * 8);
    float4 qa = qp[0], qb = qp[1];
    float q[8] = {qa.x, qa.y, qa.z, qa.w, qb.x, qb.y, qb.z, qb.w};
    float aq[8], bcv[8];
#pragma unroll
    for (int j = 0; j < 8; ++j) { aq[j] = alpha * q[j]; bcv[j] = beta + gamma * q[j]; }

    const float* hrow = hist + (size_t)brow * SS * 8;
    float accO[8];
#pragma unroll
    for (int e = 0; e < 8; ++e) accO[e] = 0.0f;

    float hreg[13][8];   // fully-unrolled -> static indices; ~4 slots live

    auto loadH = [&](int x) {
        int s = 16 * x + c;
        if (16 * x + 15 >= SS) s = min(s, SS - 1);   // folds away except last subtile
        const float4* p = reinterpret_cast<const float4*>(hrow + (size_t)s * 8);
        float4 v0 = p[0], v1 = p[1];
        float* h = hreg[x];
        h[0]=v0.x; h[1]=v0.y; h[2]=v0.z; h[3]=v0.w;
        h[4]=v1.x; h[5]=v1.y; h[6]=v1.z; h[7]=v1.w;
    };

    // pipeline state: stage-2 B-frags for two subtile parities (static [x&1] idx)
    union u_s8 { unsigned int u[4]; short8 s; };
    u_s8 hb0_[2], hb1_[2];

    // S1: att-pack -> stage-1' MFMA (4x) -> relu+pack into hb frags
    auto S1 = [&](int x) {
        const float* h = hreg[x];
        u_s8 uf;
#pragma unroll
        for (int m = 0; m < 4; ++m)
            uf.u[m] = packbf2(fmaf(bcv[2*m], h[2*m], aq[2*m]),
                              fmaf(bcv[2*m+1], h[2*m+1], aq[2*m+1]));
        f32x4 a1[4];
#pragma unroll
        for (int n = 0; n < 4; ++n)
            a1[n] = __builtin_amdgcn_mfma_f32_16x16x32_bf16(w1f[n], uf.s, b1c[n], 0, 0, 0);
        u_s8& hb0 = hb0_[x & 1];
        u_s8& hb1 = hb1_[x & 1];
#pragma unroll
        for (int q2 = 0; q2 < 2; ++q2) {
            hb0.u[q2]     = packbf2(fmaxf(a1[0][2*q2], 0.f), fmaxf(a1[0][2*q2+1], 0.f));
            hb0.u[2 + q2] = packbf2(fmaxf(a1[2][2*q2], 0.f), fmaxf(a1[2][2*q2+1], 0.f));
            hb1.u[q2]     = packbf2(fmaxf(a1[1][2*q2], 0.f), fmaxf(a1[1][2*q2+1], 0.f));
            hb1.u[2 + q2] = packbf2(fmaxf(a1[3][2*q2], 0.f), fmaxf(a1[3][2*q2+1], 0.f));
        }
    };

    // S2: stage-2' MFMA (4x) -> W3 dot -> butterfly -> mask -> pool
    auto S2 = [&](int x) {
        const float* h = hreg[x];
        u_s8& hb0 = hb0_[x & 1];
        u_s8& hb1 = hb1_[x & 1];
        f32x4 a2[2];
#pragma unroll
        for (int n2 = 0; n2 < 2; ++n2) {
            a2[n2] = __builtin_amdgcn_mfma_f32_16x16x32_bf16(w2tf[0][n2], hb0.s, b2c[n2], 0, 0, 0);
            a2[n2] = __builtin_amdgcn_mfma_f32_16x16x32_bf16(w2tf[1][n2], hb1.s, a2[n2], 0, 0, 0);
        }
        float p0 = 0.f, p1 = 0.f;
#pragma unroll
        for (int r = 0; r < 4; ++r) {
            p0 = fmaf(fmaxf(a2[0][r], 0.f), W3v[0][r], p0);
            p1 = fmaf(fmaxf(a2[1][r], 0.f), W3v[1][r], p1);
        }
        float p = p0 + p1;
        p += __shfl_xor(p, 16); p += __shfl_xor(p, 32);
        float sc = (16 * x + c < len) ? (p + b3s) : 0.0f;
#pragma unroll
        for (int e = 0; e < 8; ++e) accO[e] = fmaf(sc, h[e], accO[e]);
    };

    // ---- pipeline: load(t+3) | S1(t+1) | S2(t), fully unrolled ----
    loadH(0);
    loadH(1);
    loadH(2);
    S1(0);
#pragma unroll
    for (int it = 0; it < 13; ++it) {
        if (it + 3 < 13) loadH(it + 3);
        if (it + 1 < 13) S1(it + 1);
        S2(it);
    }

    // ---- reduce over the 16 position-lanes (g-copies identical) ----
#pragma unroll
    for (int m = 1; m < 16; m <<= 1)
#pragma unroll
        for (int e = 0; e < 8; ++e) accO[e] += __shfl_xor(accO[e], m);

    if (l == 0) {
        float4* op = reinterpret_cast<float4*>(out + (size_t)brow * 8);
        op[0] = make_float4(accO[0], accO[1], accO[2], accO[3]);
        op[1] = make_float4(accO[4], accO[5], accO[6], accO[7]);
    }
}

extern "C" void kernel_launch(void* const* d_in, const int* in_sizes, int n_in,
                              void* d_out, int out_size, void* d_ws, size_t ws_size,
                              hipStream_t stream) {
    const float* query = (const float*)d_in[0];
    const float* hist  = (const float*)d_in[1];
    const int*   hlen  = (const int*)d_in[2];
    const float* W1    = (const float*)d_in[3];
    const float* b1    = (const float*)d_in[4];
    const float* W2    = (const float*)d_in[5];
    const float* b2    = (const float*)d_in[6];
    const float* W3    = (const float*)d_in[7];
    const float* b3    = (const float*)d_in[8];
    float*       out   = (float*)d_out;

    unsigned short* wsW1 = (unsigned short*)d_ws;          // 4KB
    unsigned short* wsW2 = wsW1 + 4 * 64 * 8;              // 4KB

    prep_kernel<<<2, 256, 0, stream>>>(W1, W2, wsW1, wsW2);
    din10_kernel<<<BB / 4, 256, 0, stream>>>(query, hist, hlen, wsW1, wsW2,
                                             b1, b2, W3, b3, out);
}